// Round 7
// baseline (1203.895 us; speedup 1.0000x reference)
//
#include <hip/hip_runtime.h>
#include <hip/hip_bf16.h>

// ---------- types ----------
typedef __attribute__((ext_vector_type(8))) __bf16 bf16x8;
typedef __attribute__((ext_vector_type(4))) float f32x4;

typedef unsigned short u16;
typedef __attribute__((ext_vector_type(8))) u16 u16x8;

__device__ __forceinline__ u16 f2bf(float f) {
    unsigned int u = __float_as_uint(f);
    u += 0x7FFFu + ((u >> 16) & 1u);   // round-to-nearest-even
    return (u16)(u >> 16);
}

__device__ __forceinline__ void g2l16(const void* g, void* l) {
    __builtin_amdgcn_global_load_lds(
        (const __attribute__((address_space(1))) void*)g,
        (__attribute__((address_space(3))) void*)l, 16, 0, 0);
}

// ---------- constants ----------
#define BB 8
#define SS 1024
#define EE 768
#define HH 12
#define HD 64
#define LL 4

// ---------- fp32 -> bf16 convert ----------
__global__ __launch_bounds__(256) void cvt_k(const float* __restrict__ in,
                                             u16* __restrict__ out, int n4) {
    for (int i = blockIdx.x * 256 + threadIdx.x; i < n4; i += gridDim.x * 256) {
        float4 v = ((const float4*)in)[i];
        ushort4 u;
        u.x = f2bf(v.x); u.y = f2bf(v.y); u.z = f2bf(v.z); u.w = f2bf(v.w);
        ((ushort4*)out)[i] = u;
    }
}

// ---------- embed: h = x + wpe[study_date] ----------
__global__ __launch_bounds__(256) void embed_k(const float* __restrict__ x,
                                               const int* __restrict__ sd,
                                               const float* __restrict__ wpe,
                                               float* __restrict__ h) {
    int idx = blockIdx.x * 256 + threadIdx.x;          // over 8192*192 float4s
    int e4 = idx % 192;
    int bs = idx / 192;
    int b = bs >> 10;
    int t = (bs >> 5) & 31;
    int date = sd[b * 32 + t];
    date = date < 0 ? 0 : (date > 49 ? 49 : date);
    float4 xv = ((const float4*)x)[idx];
    float4 pv = ((const float4*)wpe)[date * 192 + e4];
    float4 r; r.x = xv.x + pv.x; r.y = xv.y + pv.y; r.z = xv.z + pv.z; r.w = xv.w + pv.w;
    ((float4*)h)[idx] = r;
}

// ---------- layernorm: wave per token ----------
template <bool BF16OUT>
__global__ __launch_bounds__(256) void ln_k(const float* __restrict__ in,
                                            const float* __restrict__ w,
                                            const float* __restrict__ b,
                                            void* __restrict__ out) {
    int tid = threadIdx.x, wv = tid >> 6, lane = tid & 63;
    int token = blockIdx.x * 4 + wv;
    const float4* ip = (const float4*)(in + (size_t)token * EE);
    float4 v[3];
#pragma unroll
    for (int p = 0; p < 3; p++) v[p] = ip[p * 64 + lane];
    float s = 0.f;
#pragma unroll
    for (int p = 0; p < 3; p++) s += v[p].x + v[p].y + v[p].z + v[p].w;
#pragma unroll
    for (int m = 1; m < 64; m <<= 1) s += __shfl_xor(s, m);
    float mean = s * (1.f / 768.f);
    float vs = 0.f;
#pragma unroll
    for (int p = 0; p < 3; p++) {
        float dx = v[p].x - mean, dy = v[p].y - mean, dz = v[p].z - mean, dw = v[p].w - mean;
        vs += dx * dx + dy * dy + dz * dz + dw * dw;
    }
#pragma unroll
    for (int m = 1; m < 64; m <<= 1) vs += __shfl_xor(vs, m);
    float rstd = rsqrtf(vs * (1.f / 768.f) + 1e-5f);
    const float4* wp = (const float4*)w;
    const float4* bp = (const float4*)b;
#pragma unroll
    for (int p = 0; p < 3; p++) {
        float4 wv4 = wp[p * 64 + lane], bv4 = bp[p * 64 + lane];
        float rx = (v[p].x - mean) * rstd * wv4.x + bv4.x;
        float ry = (v[p].y - mean) * rstd * wv4.y + bv4.y;
        float rz = (v[p].z - mean) * rstd * wv4.z + bv4.z;
        float rw = (v[p].w - mean) * rstd * wv4.w + bv4.w;
        if (BF16OUT) {
            ushort4 u; u.x = f2bf(rx); u.y = f2bf(ry); u.z = f2bf(rz); u.w = f2bf(rw);
            ((ushort4*)((u16*)out + (size_t)token * EE))[p * 64 + lane] = u;
        } else {
            float4 r; r.x = rx; r.y = ry; r.z = rz; r.w = rw;
            ((float4*)((float*)out + (size_t)token * EE))[p * 64 + lane] = r;
        }
    }
}

// ---------- GEMM: C[M,N] = A[M,K](bf16) * Bw[N,K]^T(bf16) + bias ----------
// 1-D grid, XCD-aware remap. vmcnt-gated pipeline (see R0/R4 notes):
//   BM=128: 3-stage LDS, PD=1, steady vmcnt(4). 48 KB -> 3 blocks/CU.
//   BM=64:  4-stage LDS, PD=2, steady vmcnt(6).
// R4: proj at BM=128 (0.5 ds_read/MFMA vs 0.75 at BM=64).
// R6: SPLITK=2 for proj — 384 blocks (1.5/CU, Occupancy 13.5%) underfilled the
// machine; split-K doubles grid to 768 (3/CU, one full residency round). Both
// k-halves RMW hres via unsafeAtomicAdd (global_atomic_add_f32, distinct
// addresses, device scope); bias added by the ks=0 half only.
// R5: MODE-0 V-epilogue writes vT with a per-32-token permutation pi so that
// attn's PV A-fragment is lane-local after swapped QK^T (see attn_k):
//   key j -> slot k: j<16: (j>>2)*8+(j&3); j>=16: ((j-16)>>2)*8+4+((j-16)&3)
// MODE 0: QKV epilogue  (q -> qT; k -> kT; v -> vT[B,H,HD,S] pi-permuted)
// MODE 1: residual      (hres[M,N] += C + bias)
// MODE 2: NewGELU       (outb[M,N] = bf16(gelu(C + bias)))
template <int MODE, int BM, int SPLITK>
__global__ __launch_bounds__(256) void gemm_bt(const u16* __restrict__ A,
                                               const u16* __restrict__ Bw,
                                               const float* __restrict__ bias,
                                               float* __restrict__ hres,
                                               u16* __restrict__ outb,
                                               u16* __restrict__ vT,
                                               u16* __restrict__ kT,
                                               int M, int N, int K) {
    constexpr int TM = BM / 32;              // acc m-tiles per wave (4 or 2)
    constexpr int NST = (BM == 128) ? 3 : 4; // pipeline stages
    constexpr int PD = NST - 2;              // prefetch distance (1 or 2)
    constexpr int ATILE = BM * 32;           // u16 per A stage
    constexpr int TILE = ATILE + 4096;       // u16 per stage (A+B)
    constexpr int SSTR = TILE * 2;           // stage stride bytes
    __shared__ u16 SM[NST * TILE];

    const int tid = threadIdx.x;
    const int lane = tid & 63, w = tid >> 6;
    const int quad = lane >> 4, l16 = lane & 15;

    // XCD-aware block remap (k-slice in the slowest bits)
    const int nx = N >> 7;
    const int ny = M / BM;
    int id = blockIdx.x;
    int ks = 0;
    if (SPLITK == 2) {
        const int half = ny * nx;
        ks = id >= half;
        id -= ks * half;
    }
    const int xcd = id & 7, s = id >> 3;
    const int yt = xcd * (ny >> 3) + s / nx;
    const int xt = s % nx;
    const int m0 = yt * BM, n0 = xt * 128;
    const int wm = (w >> 1) * (BM / 2), wn = (w & 1) * 64;
    const int kbase = ks * (K / SPLITK);

    f32x4 acc[TM][4];
#pragma unroll
    for (int i = 0; i < TM; i++)
#pragma unroll
        for (int j = 0; j < 4; j++) acc[i][j] = (f32x4){0.f, 0.f, 0.f, 0.f};

    const int swz = (quad ^ ((l16 >> 1) & 3)) * 8;
    const int nk = (K / SPLITK) >> 5;

    // staging: chunk c holds row (c>>2), k-chunk ((c&3)^((c>>3)&3))
    // B: 512 chunks, 2 per thread
    const int cB0 = w * 128 + lane, cB1 = cB0 + 64;
    const int rB0 = cB0 >> 2, gB0 = (((cB0 & 3) ^ ((cB0 >> 3) & 3)) * 8);
    const int rB1 = cB1 >> 2, gB1 = (((cB1 & 3) ^ ((cB1 >> 3) & 3)) * 8);
    const u16* Bp0 = Bw + (size_t)(n0 + rB0) * K + kbase + gB0;
    const u16* Bp1 = Bw + (size_t)(n0 + rB1) * K + kbase + gB1;
    char* lB0 = (char*)SM + ATILE * 2 + w * 2048;
    char* lB1 = lB0 + 1024;
    // A: BM*4 chunks (2 per thread at BM=128, 1 at BM=64)
    const int cA0 = (BM == 128) ? cB0 : tid;
    const int rA0 = cA0 >> 2, gA0 = (((cA0 & 3) ^ ((cA0 >> 3) & 3)) * 8);
    const u16* Ap0 = A + (size_t)(m0 + rA0) * K + kbase + gA0;
    char* lA0 = (char*)SM + ((BM == 128) ? w * 2048 : w * 1024);
    const int cA1 = cB1;
    const int rA1 = cA1 >> 2, gA1 = (((cA1 & 3) ^ ((cA1 >> 3) & 3)) * 8);
    const u16* Ap1 = A + (size_t)(m0 + rA1) * K + kbase + gA1;
    char* lA1 = (char*)SM + w * 2048 + 1024;

    // prologue: stage tiles 0..PD-1
    g2l16(Ap0, lA0);
    if (BM == 128) g2l16(Ap1, lA1);
    g2l16(Bp0, lB0);
    g2l16(Bp1, lB1);
    if (PD == 2) {
        g2l16(Ap0 + 32, lA0 + SSTR);
        if (BM == 128) g2l16(Ap1 + 32, lA1 + SSTR);
        g2l16(Bp0 + 32, lB0 + SSTR);
        g2l16(Bp1 + 32, lB1 + SSTR);
    }

    int rb = 0, wb = PD;
    for (int ki = 0; ki < nk; ki++) {
        if (ki + PD < nk) {
            const int kb = (ki + PD) << 5;
            const int bo = wb * SSTR;
            g2l16(Ap0 + kb, lA0 + bo);
            if (BM == 128) g2l16(Ap1 + kb, lA1 + bo);
            g2l16(Bp0 + kb, lB0 + bo);
            g2l16(Bp1 + kb, lB1 + bo);
        }
        // gate: tile ki landed when <= PD tiles' loads remain outstanding
        if (BM == 128) {
            if (ki < nk - 1) __builtin_amdgcn_s_waitcnt(0x0F74);  // vmcnt(4)
            else             __builtin_amdgcn_s_waitcnt(0x0F70);  // vmcnt(0)
        } else {
            if (ki < nk - 2)      __builtin_amdgcn_s_waitcnt(0x0F76);  // vmcnt(6)
            else if (ki == nk - 2) __builtin_amdgcn_s_waitcnt(0x0F73); // vmcnt(3)
            else                  __builtin_amdgcn_s_waitcnt(0x0F70);  // vmcnt(0)
        }
        __builtin_amdgcn_s_barrier();

        const u16* Ab = (const u16*)SM + rb * TILE;
        const u16* Bb = Ab + ATILE;
        bf16x8 af[TM], bfr[4];
#pragma unroll
        for (int t = 0; t < TM; t++)
            af[t] = *(const bf16x8*)(Ab + (wm + t * 16 + l16) * 32 + swz);
#pragma unroll
        for (int t = 0; t < 4; t++)
            bfr[t] = *(const bf16x8*)(Bb + (wn + t * 16 + l16) * 32 + swz);
#pragma unroll
        for (int tm = 0; tm < TM; tm++)
#pragma unroll
            for (int tn = 0; tn < 4; tn++)
                acc[tm][tn] = __builtin_amdgcn_mfma_f32_16x16x32_bf16(
                    af[tm], bfr[tn], acc[tm][tn], 0, 0, 0);
        rb = (rb + 1 == NST) ? 0 : rb + 1;
        wb = (wb + 1 == NST) ? 0 : wb + 1;
    }

    // epilogue: C row = m0+wm+tm*16+quad*4+r ; col = n0+wn+tn*16+l16
#pragma unroll
    for (int tm = 0; tm < TM; tm++) {
        int rowm = m0 + wm + tm * 16 + quad * 4;
#pragma unroll
        for (int tn = 0; tn < 4; tn++) {
            int coln = n0 + wn + tn * 16 + l16;
            float bv = bias[coln];
            f32x4 v = acc[tm][tn];
            if (MODE == 0) {
                int b = rowm >> 10, s2 = rowm & 1023;
                if (coln < EE) {
                    int hh = coln >> 6, d = coln & 63;
                    u16* qp = outb + ((size_t)(b * HH + hh) * SS + s2) * HD + d;
#pragma unroll
                    for (int r = 0; r < 4; r++) qp[r * HD] = f2bf(v[r] + bv);
                } else if (coln < 2 * EE) {
                    int hh = (coln - EE) >> 6, d = (coln - EE) & 63;
                    u16* kp = kT + ((size_t)(b * HH + hh) * SS + s2) * HD + d;
#pragma unroll
                    for (int r = 0; r < 4; r++) kp[r * HD] = f2bf(v[r] + bv);
                } else {
                    int hh = (coln - 2 * EE) >> 6, d = (coln - 2 * EE) & 63;
                    // pi-permute within the 32-token tile (see attn_k PV layout)
                    int j0 = s2 & 31;
                    int k0 = (j0 < 16) ? ((j0 >> 2) * 8) : (((j0 - 16) >> 2) * 8 + 4);
                    int s2p = (s2 & ~31) | k0;
                    ushort4 pk;
                    pk.x = f2bf(v[0] + bv); pk.y = f2bf(v[1] + bv);
                    pk.z = f2bf(v[2] + bv); pk.w = f2bf(v[3] + bv);
                    *(ushort4*)(vT + (((size_t)((b * HH + hh) * HD + d)) << 10) + s2p) = pk;
                }
            } else if (MODE == 1) {
#pragma unroll
                for (int r = 0; r < 4; r++) {
                    size_t idx = (size_t)(rowm + r) * N + coln;
                    float addv = v[r] + ((SPLITK == 1 || ks == 0) ? bv : 0.f);
                    if (SPLITK == 2) unsafeAtomicAdd(&hres[idx], addv);
                    else             hres[idx] += addv;
                }
            } else {
#pragma unroll
                for (int r = 0; r < 4; r++) {
                    float x = v[r] + bv;
                    float t = x + 0.044715f * x * x * x;
                    float e = __expf(-1.5957691216057308f * t);  // exp(-2*sqrt(2/pi)*t)
                    float th = (1.f - e) / (1.f + e);
                    outb[(size_t)(rowm + r) * N + coln] = f2bf(0.5f * x * (1.f + th));
                }
            }
        }
    }
}

// ---------- flash attention (R5: swapped QK^T, lane-local softmax) ----------
// qT,kT: [B,H,S,HD] bf16   vT: [B,H,HD,S] bf16 (pi-permuted per 32-tok tile)
// o: [B*S, 768] bf16
// block = 4 waves = one (b, head, 64 q-rows); K/V staged in LDS.
// Swapped QK: mfma(K,Q) -> S[key][q], col=l16=q. Each lane's 8 scores all
// belong to q=l16 (keys quad*4+r and 16+quad*4+r) -> softmax is 7 local ops +
// 2 shfl_xor (x16,x32) per reduction instead of 16 shuffles; P never touches
// LDS (the lane's exp'd values ARE its PV A-fragment, in pi key order).
// Defer-max (THR=8): skip of-rescale when tile max grows <= 8 (P <= e^8,
// fine in bf16; checked wave-uniformly via __all each tile).
__global__ __launch_bounds__(256) void attn_k(const u16* __restrict__ qT,
                                              const u16* __restrict__ kT,
                                              const u16* __restrict__ vT,
                                              u16* __restrict__ o) {
    __shared__ u16 Ks[2048];        // 32 tokens x 64 d, 16B chunks swizzled
    __shared__ u16 Vs[2048];        // 64 d x 32 pi-slots, 16B chunks swizzled
    int tid = threadIdx.x, w = tid >> 6, lane = tid & 63;
    int quad = lane >> 4, l16 = lane & 15;
    int blk = blockIdx.x;
    int qg = 15 - (blk / 96);       // largest q-groups dispatch first (load balance)
    int bh = blk % 96;              // b*12 + h
    int b = bh / HH, hh = bh % HH;
    int q0 = qg * 64;
    int kend_blk = q0 + 64;
    int kend_w = q0 + ((w >> 1) ? 64 : 32);

    const u16* qbase = qT + ((size_t)bh * SS + q0 + w * 16 + l16) * HD + quad * 8;
    bf16x8 qf0 = *(const bf16x8*)(qbase);
    bf16x8 qf1 = *(const bf16x8*)(qbase + 32);

    f32x4 of[4];
#pragma unroll
    for (int i = 0; i < 4; i++) of[i] = (f32x4){0.f, 0.f, 0.f, 0.f};
    float mrun = -__builtin_inff(), lrun = 0.f;

    // staging addresses: slot s (=tid) of Ks holds K[token=s>>3][dchunk=(s&7)^(token&7)]
    int tK = tid >> 3, dcK = ((tid & 7) ^ (tK & 7));
    const u16* kg = kT + ((size_t)bh * SS + tK) * HD + dcK * 8;
    char* kl = (char*)Ks + w * 1024;
    // slot s of Vs holds V[d=s>>2][pi-tokchunk=(s&3)^((d>>1)&3)]
    int dV = tid >> 2, tcV = ((tid & 3) ^ ((dV >> 1) & 3));
    const u16* vg = vT + ((size_t)bh * HD + dV) * SS + tcV * 8;
    char* vl = (char*)Vs + w * 1024;

    for (int kb = 0; kb < kend_blk; kb += 32) {
        g2l16(kg + (size_t)kb * HD, kl);
        g2l16(vg + kb, vl);
        __syncthreads();
        if (kb < kend_w) {
            int t0 = l16, t1 = 16 + l16;
            bf16x8 k00 = *(const bf16x8*)(Ks + (t0 * 8 + (quad ^ (l16 & 7))) * 8);
            bf16x8 k01 = *(const bf16x8*)(Ks + (t0 * 8 + ((4 + quad) ^ (l16 & 7))) * 8);
            bf16x8 k10 = *(const bf16x8*)(Ks + (t1 * 8 + (quad ^ (l16 & 7))) * 8);
            bf16x8 k11 = *(const bf16x8*)(Ks + (t1 * 8 + ((4 + quad) ^ (l16 & 7))) * 8);
            // swapped: D[key][q]  (sT0 keys quad*4+r, sT1 keys 16+quad*4+r; col=l16=q)
            f32x4 sT0 = (f32x4){0.f, 0.f, 0.f, 0.f};
            f32x4 sT1 = (f32x4){0.f, 0.f, 0.f, 0.f};
            sT0 = __builtin_amdgcn_mfma_f32_16x16x32_bf16(k00, qf0, sT0, 0, 0, 0);
            sT0 = __builtin_amdgcn_mfma_f32_16x16x32_bf16(k01, qf1, sT0, 0, 0, 0);
            sT1 = __builtin_amdgcn_mfma_f32_16x16x32_bf16(k10, qf0, sT1, 0, 0, 0);
            sT1 = __builtin_amdgcn_mfma_f32_16x16x32_bf16(k11, qf1, sT1, 0, 0, 0);

            float a0[4], a1[4];
#pragma unroll
            for (int r = 0; r < 4; r++) { a0[r] = sT0[r] * 0.125f; a1[r] = sT1[r] * 0.125f; }
            // tile max for q=l16: 7 local + 2 cross-quad shuffles
            float mx = fmaxf(fmaxf(fmaxf(a0[0], a0[1]), fmaxf(a0[2], a0[3])),
                             fmaxf(fmaxf(a1[0], a1[1]), fmaxf(a1[2], a1[3])));
            mx = fmaxf(mx, __shfl_xor(mx, 16));
            mx = fmaxf(mx, __shfl_xor(mx, 32));
            // defer-max: only rescale when max grew by > 8
            if (!__all(mx - mrun <= 8.0f)) {
                float mnew = fmaxf(mrun, mx);
                float alpha = __expf(mrun - mnew);
                mrun = mnew;
                lrun *= alpha;
                float al[4];
#pragma unroll
                for (int r = 0; r < 4; r++) al[r] = __shfl(alpha, quad * 4 + r);
#pragma unroll
                for (int n4 = 0; n4 < 4; n4++) {
                    of[n4][0] *= al[0]; of[n4][1] *= al[1];
                    of[n4][2] *= al[2]; of[n4][3] *= al[3];
                }
            }
            float p0[4], p1[4];
#pragma unroll
            for (int r = 0; r < 4; r++) {
                p0[r] = __expf(a0[r] - mrun);
                p1[r] = __expf(a1[r] - mrun);
            }
            float ps = ((p0[0] + p0[1]) + (p0[2] + p0[3])) +
                       ((p1[0] + p1[1]) + (p1[2] + p1[3]));
            ps += __shfl_xor(ps, 16);
            ps += __shfl_xor(ps, 32);
            lrun += ps;
            // PV A-frag: lane-local (pi key order: e<4 -> key quad*4+e, else 16+quad*4+e-4)
            union { u16x8 u; bf16x8 v; } pa;
            pa.u[0] = f2bf(p0[0]); pa.u[1] = f2bf(p0[1]);
            pa.u[2] = f2bf(p0[2]); pa.u[3] = f2bf(p0[3]);
            pa.u[4] = f2bf(p1[0]); pa.u[5] = f2bf(p1[1]);
            pa.u[6] = f2bf(p1[2]); pa.u[7] = f2bf(p1[3]);
#pragma unroll
            for (int n4 = 0; n4 < 4; n4++) {
                int d = n4 * 16 + l16;
                bf16x8 vf = *(const bf16x8*)(Vs + (d * 4 + (quad ^ ((d >> 1) & 3))) * 8);
                of[n4] = __builtin_amdgcn_mfma_f32_16x16x32_bf16(pa.v, vf, of[n4], 0, 0, 0);
            }
        }
        __syncthreads();
    }

    float linv[4];
#pragma unroll
    for (int r = 0; r < 4; r++) linv[r] = 1.f / __shfl(lrun, quad * 4 + r);
#pragma unroll
    for (int n4 = 0; n4 < 4; n4++)
#pragma unroll
        for (int r = 0; r < 4; r++)
            o[(size_t)(b * SS + q0 + w * 16 + quad * 4 + r) * EE + hh * HD + n4 * 16 + l16] =
                f2bf(of[n4][r] * linv[r]);
}

// ---------- launcher ----------
extern "C" void kernel_launch(void* const* d_in, const int* in_sizes, int n_in,
                              void* d_out, int out_size, void* d_ws, size_t ws_size,
                              hipStream_t stream) {
    const float* x     = (const float*)d_in[0];
    const int*   sd    = (const int*)d_in[1];
    const float* wpe   = (const float*)d_in[2];
    const float* ln1w  = (const float*)d_in[3];
    const float* ln1b  = (const float*)d_in[4];
    const float* in_w  = (const float*)d_in[5];
    const float* in_b  = (const float*)d_in[6];
    const float* out_w = (const float*)d_in[7];
    const float* out_b = (const float*)d_in[8];
    const float* ln2w  = (const float*)d_in[9];
    const float* ln2b  = (const float*)d_in[10];
    const float* fc_w  = (const float*)d_in[11];
    const float* fc_b  = (const float*)d_in[12];
    const float* pr_w  = (const float*)d_in[13];
    const float* pr_b  = (const float*)d_in[14];
    const float* lnfw  = (const float*)d_in[15];
    const float* lnfb  = (const float*)d_in[16];
    float* outp = (float*)d_out;

    char* ws = (char*)d_ws;
    float* h   = (float*)ws;                        // 25,165,824 B
    u16* ybuf  = (u16*)(ws + 25165824);             // 12,582,912 B
    u16* big   = (u16*)(ws + 37748736);             // 50,331,648 B (qT+kT / fc act)
    u16* qT    = big;                               // 6,291,456 elems
    u16* kT    = big + 6291456;                     // 6,291,456 elems
    u16* vT    = (u16*)(ws + 88080384);             // 12,582,912 B
    u16* wb    = (u16*)(ws + 100663296);            // 56,623,104 B
    u16* w_in  = wb;                                // 4*2304*768
    u16* w_out = w_in + 7077888;                    // 4*768*768
    u16* w_fc  = w_out + 2359296;                   // 4*3072*768
    u16* w_pr  = w_fc + 9437184;                    // 4*768*3072

    cvt_k<<<1024, 256, 0, stream>>>(in_w,  w_in,  7077888 / 4);
    cvt_k<<<1024, 256, 0, stream>>>(out_w, w_out, 2359296 / 4);
    cvt_k<<<1024, 256, 0, stream>>>(fc_w,  w_fc,  9437184 / 4);
    cvt_k<<<1024, 256, 0, stream>>>(pr_w,  w_pr,  9437184 / 4);
    embed_k<<<6144, 256, 0, stream>>>(x, sd, wpe, h);

    for (int l = 0; l < LL; l++) {
        ln_k<true><<<2048, 256, 0, stream>>>(h, ln1w + l * EE, ln1b + l * EE, ybuf);
        gemm_bt<0, 128, 1><<<18 * 64, 256, 0, stream>>>(
            ybuf, w_in + (size_t)l * 2304 * 768, in_b + l * 2304, nullptr, qT, vT, kT,
            8192, 2304, 768);
        attn_k<<<1536, 256, 0, stream>>>(qT, kT, vT, ybuf);
        gemm_bt<1, 64, 1><<<6 * 128, 256, 0, stream>>>(
            ybuf, w_out + (size_t)l * 768 * 768, out_b + l * 768, h, nullptr, nullptr, nullptr,
            8192, 768, 768);
        ln_k<true><<<2048, 256, 0, stream>>>(h, ln2w + l * EE, ln2b + l * EE, ybuf);
        gemm_bt<2, 128, 1><<<24 * 64, 256, 0, stream>>>(
            ybuf, w_fc + (size_t)l * 3072 * 768, fc_b + l * 3072, nullptr, big, nullptr, nullptr,
            8192, 3072, 768);
        gemm_bt<1, 128, 2><<<2 * 6 * 64, 256, 0, stream>>>(
            big, w_pr + (size_t)l * 768 * 3072, pr_b + l * 768, h, nullptr, nullptr, nullptr,
            8192, 768, 3072);
    }
    ln_k<false><<<2048, 256, 0, stream>>>(h, lnfw, lnfb, outp);
}

// Round 8
// 1170.174 us; speedup vs baseline: 1.0288x; 1.0288x over previous
//
#include <hip/hip_runtime.h>
#include <hip/hip_bf16.h>

// ---------- types ----------
typedef __attribute__((ext_vector_type(8))) __bf16 bf16x8;
typedef __attribute__((ext_vector_type(4))) float f32x4;

typedef unsigned short u16;
typedef __attribute__((ext_vector_type(8))) u16 u16x8;

__device__ __forceinline__ u16 f2bf(float f) {
    unsigned int u = __float_as_uint(f);
    u += 0x7FFFu + ((u >> 16) & 1u);   // round-to-nearest-even
    return (u16)(u >> 16);
}

__device__ __forceinline__ void g2l16(const void* g, void* l) {
    __builtin_amdgcn_global_load_lds(
        (const __attribute__((address_space(1))) void*)g,
        (__attribute__((address_space(3))) void*)l, 16, 0, 0);
}

// ---------- constants ----------
#define BB 8
#define SS 1024
#define EE 768
#define HH 12
#define HD 64
#define LL 4

// ---------- fp32 -> bf16 convert ----------
__global__ __launch_bounds__(256) void cvt_k(const float* __restrict__ in,
                                             u16* __restrict__ out, int n4) {
    for (int i = blockIdx.x * 256 + threadIdx.x; i < n4; i += gridDim.x * 256) {
        float4 v = ((const float4*)in)[i];
        ushort4 u;
        u.x = f2bf(v.x); u.y = f2bf(v.y); u.z = f2bf(v.z); u.w = f2bf(v.w);
        ((ushort4*)out)[i] = u;
    }
}

// ---------- embed: h = x + wpe[study_date] ----------
__global__ __launch_bounds__(256) void embed_k(const float* __restrict__ x,
                                               const int* __restrict__ sd,
                                               const float* __restrict__ wpe,
                                               float* __restrict__ h) {
    int idx = blockIdx.x * 256 + threadIdx.x;          // over 8192*192 float4s
    int e4 = idx % 192;
    int bs = idx / 192;
    int b = bs >> 10;
    int t = (bs >> 5) & 31;
    int date = sd[b * 32 + t];
    date = date < 0 ? 0 : (date > 49 ? 49 : date);
    float4 xv = ((const float4*)x)[idx];
    float4 pv = ((const float4*)wpe)[date * 192 + e4];
    float4 r; r.x = xv.x + pv.x; r.y = xv.y + pv.y; r.z = xv.z + pv.z; r.w = xv.w + pv.w;
    ((float4*)h)[idx] = r;
}

// ---------- layernorm: wave per token ----------
template <bool BF16OUT>
__global__ __launch_bounds__(256) void ln_k(const float* __restrict__ in,
                                            const float* __restrict__ w,
                                            const float* __restrict__ b,
                                            void* __restrict__ out) {
    int tid = threadIdx.x, wv = tid >> 6, lane = tid & 63;
    int token = blockIdx.x * 4 + wv;
    const float4* ip = (const float4*)(in + (size_t)token * EE);
    float4 v[3];
#pragma unroll
    for (int p = 0; p < 3; p++) v[p] = ip[p * 64 + lane];
    float s = 0.f;
#pragma unroll
    for (int p = 0; p < 3; p++) s += v[p].x + v[p].y + v[p].z + v[p].w;
#pragma unroll
    for (int m = 1; m < 64; m <<= 1) s += __shfl_xor(s, m);
    float mean = s * (1.f / 768.f);
    float vs = 0.f;
#pragma unroll
    for (int p = 0; p < 3; p++) {
        float dx = v[p].x - mean, dy = v[p].y - mean, dz = v[p].z - mean, dw = v[p].w - mean;
        vs += dx * dx + dy * dy + dz * dz + dw * dw;
    }
#pragma unroll
    for (int m = 1; m < 64; m <<= 1) vs += __shfl_xor(vs, m);
    float rstd = rsqrtf(vs * (1.f / 768.f) + 1e-5f);
    const float4* wp = (const float4*)w;
    const float4* bp = (const float4*)b;
#pragma unroll
    for (int p = 0; p < 3; p++) {
        float4 wv4 = wp[p * 64 + lane], bv4 = bp[p * 64 + lane];
        float rx = (v[p].x - mean) * rstd * wv4.x + bv4.x;
        float ry = (v[p].y - mean) * rstd * wv4.y + bv4.y;
        float rz = (v[p].z - mean) * rstd * wv4.z + bv4.z;
        float rw = (v[p].w - mean) * rstd * wv4.w + bv4.w;
        if (BF16OUT) {
            ushort4 u; u.x = f2bf(rx); u.y = f2bf(ry); u.z = f2bf(rz); u.w = f2bf(rw);
            ((ushort4*)((u16*)out + (size_t)token * EE))[p * 64 + lane] = u;
        } else {
            float4 r; r.x = rx; r.y = ry; r.z = rz; r.w = rw;
            ((float4*)((float*)out + (size_t)token * EE))[p * 64 + lane] = r;
        }
    }
}

// ---------- GEMM: C[M,N] = A[M,K](bf16) * Bw[N,K]^T(bf16) + bias ----------
// 1-D grid, XCD-aware remap. vmcnt-gated pipeline (never vmcnt(0) in steady
// state; see R0/R4 notes). NST now per-shape (R7):
//   QKV/FC (BM=128, grid >= 3/CU): NST=3, PD=1, 48 KB -> 3 blocks/CU.
//   proj   (BM=128, grid 1.5/CU):  NST=4, PD=2, 64 KB -> 2/CU cap, no residency
//     loss at 384 blocks; PD=2 gives ~2 iters (~1700 cyc) of issue-to-gate
//     coverage > ~900 cyc HBM first-touch latency on read-once A.
//   out    (BM=64): NST=4, PD=2, 48 KB (unchanged).
// R7: split-K reverted — atomics doubled WRITE (24.6->48 MB) and cost more
// than the occupancy gain (69.2->74.0 µs despite 13.5->24.7% occupancy).
// R5: MODE-0 V-epilogue writes vT pi-permuted per 32-token tile (see attn_k).
// MODE 0: QKV epilogue  (q -> qT; k -> kT; v -> vT[B,H,HD,S] pi-permuted)
// MODE 1: residual      (hres[M,N] += C + bias)
// MODE 2: NewGELU       (outb[M,N] = bf16(gelu(C + bias)))
template <int MODE, int BM, int NST>
__global__ __launch_bounds__(256) void gemm_bt(const u16* __restrict__ A,
                                               const u16* __restrict__ Bw,
                                               const float* __restrict__ bias,
                                               float* __restrict__ hres,
                                               u16* __restrict__ outb,
                                               u16* __restrict__ vT,
                                               u16* __restrict__ kT,
                                               int M, int N, int K) {
    constexpr int TM = BM / 32;              // acc m-tiles per wave (4 or 2)
    constexpr int PD = NST - 2;              // prefetch distance
    constexpr int ATILE = BM * 32;           // u16 per A stage
    constexpr int TILE = ATILE + 4096;       // u16 per stage (A+B)
    constexpr int SSTR = TILE * 2;           // stage stride bytes
    __shared__ u16 SM[NST * TILE];

    const int tid = threadIdx.x;
    const int lane = tid & 63, w = tid >> 6;
    const int quad = lane >> 4, l16 = lane & 15;

    // XCD-aware block remap
    const int nx = N >> 7;
    const int ny = M / BM;
    const int id = blockIdx.x;
    const int xcd = id & 7, s = id >> 3;
    const int yt = xcd * (ny >> 3) + s / nx;
    const int xt = s % nx;
    const int m0 = yt * BM, n0 = xt * 128;
    const int wm = (w >> 1) * (BM / 2), wn = (w & 1) * 64;

    f32x4 acc[TM][4];
#pragma unroll
    for (int i = 0; i < TM; i++)
#pragma unroll
        for (int j = 0; j < 4; j++) acc[i][j] = (f32x4){0.f, 0.f, 0.f, 0.f};

    const int swz = (quad ^ ((l16 >> 1) & 3)) * 8;
    const int nk = K >> 5;

    // staging: chunk c holds row (c>>2), k-chunk ((c&3)^((c>>3)&3))
    // B: 512 chunks, 2 per thread
    const int cB0 = w * 128 + lane, cB1 = cB0 + 64;
    const int rB0 = cB0 >> 2, gB0 = (((cB0 & 3) ^ ((cB0 >> 3) & 3)) * 8);
    const int rB1 = cB1 >> 2, gB1 = (((cB1 & 3) ^ ((cB1 >> 3) & 3)) * 8);
    const u16* Bp0 = Bw + (size_t)(n0 + rB0) * K + gB0;
    const u16* Bp1 = Bw + (size_t)(n0 + rB1) * K + gB1;
    char* lB0 = (char*)SM + ATILE * 2 + w * 2048;
    char* lB1 = lB0 + 1024;
    // A: BM*4 chunks (2 per thread at BM=128, 1 at BM=64)
    const int cA0 = (BM == 128) ? cB0 : tid;
    const int rA0 = cA0 >> 2, gA0 = (((cA0 & 3) ^ ((cA0 >> 3) & 3)) * 8);
    const u16* Ap0 = A + (size_t)(m0 + rA0) * K + gA0;
    char* lA0 = (char*)SM + ((BM == 128) ? w * 2048 : w * 1024);
    const int cA1 = cB1;
    const int rA1 = cA1 >> 2, gA1 = (((cA1 & 3) ^ ((cA1 >> 3) & 3)) * 8);
    const u16* Ap1 = A + (size_t)(m0 + rA1) * K + gA1;
    char* lA1 = (char*)SM + w * 2048 + 1024;

    // prologue: stage tiles 0..PD-1
#pragma unroll
    for (int p = 0; p < PD; p++) {
        g2l16(Ap0 + p * 32, lA0 + p * SSTR);
        if (BM == 128) g2l16(Ap1 + p * 32, lA1 + p * SSTR);
        g2l16(Bp0 + p * 32, lB0 + p * SSTR);
        g2l16(Bp1 + p * 32, lB1 + p * SSTR);
    }

    int rb = 0, wb = PD;
    for (int ki = 0; ki < nk; ki++) {
        if (ki + PD < nk) {
            const int kb = (ki + PD) << 5;
            const int bo = wb * SSTR;
            g2l16(Ap0 + kb, lA0 + bo);
            if (BM == 128) g2l16(Ap1 + kb, lA1 + bo);
            g2l16(Bp0 + kb, lB0 + bo);
            g2l16(Bp1 + kb, lB1 + bo);
        }
        // gate: tile ki landed when <= d tile-groups remain outstanding,
        // d = min(PD, nk-1-ki); loads/group = 4 (BM=128) or 3 (BM=64)
        {
            const int rem = nk - 1 - ki;
            const int d = rem < PD ? rem : PD;
            if (BM == 128) {
                if (PD == 2) {
                    if (d == 2)      __builtin_amdgcn_s_waitcnt(0x0F78);  // vmcnt(8)
                    else if (d == 1) __builtin_amdgcn_s_waitcnt(0x0F74);  // vmcnt(4)
                    else             __builtin_amdgcn_s_waitcnt(0x0F70);  // vmcnt(0)
                } else {
                    if (d == 1)      __builtin_amdgcn_s_waitcnt(0x0F74);  // vmcnt(4)
                    else             __builtin_amdgcn_s_waitcnt(0x0F70);  // vmcnt(0)
                }
            } else {
                if (d == 2)      __builtin_amdgcn_s_waitcnt(0x0F76);  // vmcnt(6)
                else if (d == 1) __builtin_amdgcn_s_waitcnt(0x0F73);  // vmcnt(3)
                else             __builtin_amdgcn_s_waitcnt(0x0F70);  // vmcnt(0)
            }
        }
        __builtin_amdgcn_s_barrier();

        const u16* Ab = (const u16*)SM + rb * TILE;
        const u16* Bb = Ab + ATILE;
        bf16x8 af[TM], bfr[4];
#pragma unroll
        for (int t = 0; t < TM; t++)
            af[t] = *(const bf16x8*)(Ab + (wm + t * 16 + l16) * 32 + swz);
#pragma unroll
        for (int t = 0; t < 4; t++)
            bfr[t] = *(const bf16x8*)(Bb + (wn + t * 16 + l16) * 32 + swz);
#pragma unroll
        for (int tm = 0; tm < TM; tm++)
#pragma unroll
            for (int tn = 0; tn < 4; tn++)
                acc[tm][tn] = __builtin_amdgcn_mfma_f32_16x16x32_bf16(
                    af[tm], bfr[tn], acc[tm][tn], 0, 0, 0);
        rb = (rb + 1 == NST) ? 0 : rb + 1;
        wb = (wb + 1 == NST) ? 0 : wb + 1;
    }

    // epilogue: C row = m0+wm+tm*16+quad*4+r ; col = n0+wn+tn*16+l16
#pragma unroll
    for (int tm = 0; tm < TM; tm++) {
        int rowm = m0 + wm + tm * 16 + quad * 4;
#pragma unroll
        for (int tn = 0; tn < 4; tn++) {
            int coln = n0 + wn + tn * 16 + l16;
            float bv = bias[coln];
            f32x4 v = acc[tm][tn];
            if (MODE == 0) {
                int b = rowm >> 10, s2 = rowm & 1023;
                if (coln < EE) {
                    int hh = coln >> 6, d = coln & 63;
                    u16* qp = outb + ((size_t)(b * HH + hh) * SS + s2) * HD + d;
#pragma unroll
                    for (int r = 0; r < 4; r++) qp[r * HD] = f2bf(v[r] + bv);
                } else if (coln < 2 * EE) {
                    int hh = (coln - EE) >> 6, d = (coln - EE) & 63;
                    u16* kp = kT + ((size_t)(b * HH + hh) * SS + s2) * HD + d;
#pragma unroll
                    for (int r = 0; r < 4; r++) kp[r * HD] = f2bf(v[r] + bv);
                } else {
                    int hh = (coln - 2 * EE) >> 6, d = (coln - 2 * EE) & 63;
                    // pi-permute within the 32-token tile (see attn_k PV layout)
                    int j0 = s2 & 31;
                    int k0 = (j0 < 16) ? ((j0 >> 2) * 8) : (((j0 - 16) >> 2) * 8 + 4);
                    int s2p = (s2 & ~31) | k0;
                    ushort4 pk;
                    pk.x = f2bf(v[0] + bv); pk.y = f2bf(v[1] + bv);
                    pk.z = f2bf(v[2] + bv); pk.w = f2bf(v[3] + bv);
                    *(ushort4*)(vT + (((size_t)((b * HH + hh) * HD + d)) << 10) + s2p) = pk;
                }
            } else if (MODE == 1) {
#pragma unroll
                for (int r = 0; r < 4; r++) {
                    size_t idx = (size_t)(rowm + r) * N + coln;
                    hres[idx] += v[r] + bv;
                }
            } else {
#pragma unroll
                for (int r = 0; r < 4; r++) {
                    float x = v[r] + bv;
                    float t = x + 0.044715f * x * x * x;
                    float e = __expf(-1.5957691216057308f * t);  // exp(-2*sqrt(2/pi)*t)
                    float th = (1.f - e) / (1.f + e);
                    outb[(size_t)(rowm + r) * N + coln] = f2bf(0.5f * x * (1.f + th));
                }
            }
        }
    }
}

// ---------- flash attention (R5: swapped QK^T, lane-local softmax) ----------
// qT,kT: [B,H,S,HD] bf16   vT: [B,H,HD,S] bf16 (pi-permuted per 32-tok tile)
// o: [B*S, 768] bf16
// block = 4 waves = one (b, head, 64 q-rows); K/V staged in LDS.
// Swapped QK: mfma(K,Q) -> S[key][q], col=l16=q. Each lane's 8 scores all
// belong to q=l16 (keys quad*4+r and 16+quad*4+r) -> softmax is 7 local ops +
// 2 shfl_xor (x16,x32) per reduction instead of 16 shuffles; P never touches
// LDS (the lane's exp'd values ARE its PV A-fragment, in pi key order).
// Defer-max (THR=8): skip of-rescale when tile max grows <= 8 (P <= e^8,
// fine in bf16; checked wave-uniformly via __all each tile).
__global__ __launch_bounds__(256) void attn_k(const u16* __restrict__ qT,
                                              const u16* __restrict__ kT,
                                              const u16* __restrict__ vT,
                                              u16* __restrict__ o) {
    __shared__ u16 Ks[2048];        // 32 tokens x 64 d, 16B chunks swizzled
    __shared__ u16 Vs[2048];        // 64 d x 32 pi-slots, 16B chunks swizzled
    int tid = threadIdx.x, w = tid >> 6, lane = tid & 63;
    int quad = lane >> 4, l16 = lane & 15;
    int blk = blockIdx.x;
    int qg = 15 - (blk / 96);       // largest q-groups dispatch first (load balance)
    int bh = blk % 96;              // b*12 + h
    int b = bh / HH, hh = bh % HH;
    int q0 = qg * 64;
    int kend_blk = q0 + 64;
    int kend_w = q0 + ((w >> 1) ? 64 : 32);

    const u16* qbase = qT + ((size_t)bh * SS + q0 + w * 16 + l16) * HD + quad * 8;
    bf16x8 qf0 = *(const bf16x8*)(qbase);
    bf16x8 qf1 = *(const bf16x8*)(qbase + 32);

    f32x4 of[4];
#pragma unroll
    for (int i = 0; i < 4; i++) of[i] = (f32x4){0.f, 0.f, 0.f, 0.f};
    float mrun = -__builtin_inff(), lrun = 0.f;

    // staging addresses: slot s (=tid) of Ks holds K[token=s>>3][dchunk=(s&7)^(token&7)]
    int tK = tid >> 3, dcK = ((tid & 7) ^ (tK & 7));
    const u16* kg = kT + ((size_t)bh * SS + tK) * HD + dcK * 8;
    char* kl = (char*)Ks + w * 1024;
    // slot s of Vs holds V[d=s>>2][pi-tokchunk=(s&3)^((d>>1)&3)]
    int dV = tid >> 2, tcV = ((tid & 3) ^ ((dV >> 1) & 3));
    const u16* vg = vT + ((size_t)bh * HD + dV) * SS + tcV * 8;
    char* vl = (char*)Vs + w * 1024;

    for (int kb = 0; kb < kend_blk; kb += 32) {
        g2l16(kg + (size_t)kb * HD, kl);
        g2l16(vg + kb, vl);
        __syncthreads();
        if (kb < kend_w) {
            int t0 = l16, t1 = 16 + l16;
            bf16x8 k00 = *(const bf16x8*)(Ks + (t0 * 8 + (quad ^ (l16 & 7))) * 8);
            bf16x8 k01 = *(const bf16x8*)(Ks + (t0 * 8 + ((4 + quad) ^ (l16 & 7))) * 8);
            bf16x8 k10 = *(const bf16x8*)(Ks + (t1 * 8 + (quad ^ (l16 & 7))) * 8);
            bf16x8 k11 = *(const bf16x8*)(Ks + (t1 * 8 + ((4 + quad) ^ (l16 & 7))) * 8);
            // swapped: D[key][q]  (sT0 keys quad*4+r, sT1 keys 16+quad*4+r; col=l16=q)
            f32x4 sT0 = (f32x4){0.f, 0.f, 0.f, 0.f};
            f32x4 sT1 = (f32x4){0.f, 0.f, 0.f, 0.f};
            sT0 = __builtin_amdgcn_mfma_f32_16x16x32_bf16(k00, qf0, sT0, 0, 0, 0);
            sT0 = __builtin_amdgcn_mfma_f32_16x16x32_bf16(k01, qf1, sT0, 0, 0, 0);
            sT1 = __builtin_amdgcn_mfma_f32_16x16x32_bf16(k10, qf0, sT1, 0, 0, 0);
            sT1 = __builtin_amdgcn_mfma_f32_16x16x32_bf16(k11, qf1, sT1, 0, 0, 0);

            float a0[4], a1[4];
#pragma unroll
            for (int r = 0; r < 4; r++) { a0[r] = sT0[r] * 0.125f; a1[r] = sT1[r] * 0.125f; }
            // tile max for q=l16: 7 local + 2 cross-quad shuffles
            float mx = fmaxf(fmaxf(fmaxf(a0[0], a0[1]), fmaxf(a0[2], a0[3])),
                             fmaxf(fmaxf(a1[0], a1[1]), fmaxf(a1[2], a1[3])));
            mx = fmaxf(mx, __shfl_xor(mx, 16));
            mx = fmaxf(mx, __shfl_xor(mx, 32));
            // defer-max: only rescale when max grew by > 8
            if (!__all(mx - mrun <= 8.0f)) {
                float mnew = fmaxf(mrun, mx);
                float alpha = __expf(mrun - mnew);
                mrun = mnew;
                lrun *= alpha;
                float al[4];
#pragma unroll
                for (int r = 0; r < 4; r++) al[r] = __shfl(alpha, quad * 4 + r);
#pragma unroll
                for (int n4 = 0; n4 < 4; n4++) {
                    of[n4][0] *= al[0]; of[n4][1] *= al[1];
                    of[n4][2] *= al[2]; of[n4][3] *= al[3];
                }
            }
            float p0[4], p1[4];
#pragma unroll
            for (int r = 0; r < 4; r++) {
                p0[r] = __expf(a0[r] - mrun);
                p1[r] = __expf(a1[r] - mrun);
            }
            float ps = ((p0[0] + p0[1]) + (p0[2] + p0[3])) +
                       ((p1[0] + p1[1]) + (p1[2] + p1[3]));
            ps += __shfl_xor(ps, 16);
            ps += __shfl_xor(ps, 32);
            lrun += ps;
            // PV A-frag: lane-local (pi key order: e<4 -> key quad*4+e, else 16+quad*4+e-4)
            union { u16x8 u; bf16x8 v; } pa;
            pa.u[0] = f2bf(p0[0]); pa.u[1] = f2bf(p0[1]);
            pa.u[2] = f2bf(p0[2]); pa.u[3] = f2bf(p0[3]);
            pa.u[4] = f2bf(p1[0]); pa.u[5] = f2bf(p1[1]);
            pa.u[6] = f2bf(p1[2]); pa.u[7] = f2bf(p1[3]);
#pragma unroll
            for (int n4 = 0; n4 < 4; n4++) {
                int d = n4 * 16 + l16;
                bf16x8 vf = *(const bf16x8*)(Vs + (d * 4 + (quad ^ ((d >> 1) & 3))) * 8);
                of[n4] = __builtin_amdgcn_mfma_f32_16x16x32_bf16(pa.v, vf, of[n4], 0, 0, 0);
            }
        }
        __syncthreads();
    }

    float linv[4];
#pragma unroll
    for (int r = 0; r < 4; r++) linv[r] = 1.f / __shfl(lrun, quad * 4 + r);
#pragma unroll
    for (int n4 = 0; n4 < 4; n4++)
#pragma unroll
        for (int r = 0; r < 4; r++)
            o[(size_t)(b * SS + q0 + w * 16 + quad * 4 + r) * EE + hh * HD + n4 * 16 + l16] =
                f2bf(of[n4][r] * linv[r]);
}

// ---------- launcher ----------
extern "C" void kernel_launch(void* const* d_in, const int* in_sizes, int n_in,
                              void* d_out, int out_size, void* d_ws, size_t ws_size,
                              hipStream_t stream) {
    const float* x     = (const float*)d_in[0];
    const int*   sd    = (const int*)d_in[1];
    const float* wpe   = (const float*)d_in[2];
    const float* ln1w  = (const float*)d_in[3];
    const float* ln1b  = (const float*)d_in[4];
    const float* in_w  = (const float*)d_in[5];
    const float* in_b  = (const float*)d_in[6];
    const float* out_w = (const float*)d_in[7];
    const float* out_b = (const float*)d_in[8];
    const float* ln2w  = (const float*)d_in[9];
    const float* ln2b  = (const float*)d_in[10];
    const float* fc_w  = (const float*)d_in[11];
    const float* fc_b  = (const float*)d_in[12];
    const float* pr_w  = (const float*)d_in[13];
    const float* pr_b  = (const float*)d_in[14];
    const float* lnfw  = (const float*)d_in[15];
    const float* lnfb  = (const float*)d_in[16];
    float* outp = (float*)d_out;

    char* ws = (char*)d_ws;
    float* h   = (float*)ws;                        // 25,165,824 B
    u16* ybuf  = (u16*)(ws + 25165824);             // 12,582,912 B
    u16* big   = (u16*)(ws + 37748736);             // 50,331,648 B (qT+kT / fc act)
    u16* qT    = big;                               // 6,291,456 elems
    u16* kT    = big + 6291456;                     // 6,291,456 elems
    u16* vT    = (u16*)(ws + 88080384);             // 12,582,912 B
    u16* wb    = (u16*)(ws + 100663296);            // 56,623,104 B
    u16* w_in  = wb;                                // 4*2304*768
    u16* w_out = w_in + 7077888;                    // 4*768*768
    u16* w_fc  = w_out + 2359296;                   // 4*3072*768
    u16* w_pr  = w_fc + 9437184;                    // 4*768*3072

    cvt_k<<<1024, 256, 0, stream>>>(in_w,  w_in,  7077888 / 4);
    cvt_k<<<1024, 256, 0, stream>>>(out_w, w_out, 2359296 / 4);
    cvt_k<<<1024, 256, 0, stream>>>(fc_w,  w_fc,  9437184 / 4);
    cvt_k<<<1024, 256, 0, stream>>>(pr_w,  w_pr,  9437184 / 4);
    embed_k<<<6144, 256, 0, stream>>>(x, sd, wpe, h);

    for (int l = 0; l < LL; l++) {
        ln_k<true><<<2048, 256, 0, stream>>>(h, ln1w + l * EE, ln1b + l * EE, ybuf);
        gemm_bt<0, 128, 3><<<18 * 64, 256, 0, stream>>>(
            ybuf, w_in + (size_t)l * 2304 * 768, in_b + l * 2304, nullptr, qT, vT, kT,
            8192, 2304, 768);
        attn_k<<<1536, 256, 0, stream>>>(qT, kT, vT, ybuf);
        gemm_bt<1, 64, 4><<<6 * 128, 256, 0, stream>>>(
            ybuf, w_out + (size_t)l * 768 * 768, out_b + l * 768, h, nullptr, nullptr, nullptr,
            8192, 768, 768);
        ln_k<true><<<2048, 256, 0, stream>>>(h, ln2w + l * EE, ln2b + l * EE, ybuf);
        gemm_bt<2, 128, 3><<<24 * 64, 256, 0, stream>>>(
            ybuf, w_fc + (size_t)l * 3072 * 768, fc_b + l * 3072, nullptr, big, nullptr, nullptr,
            8192, 3072, 768);
        gemm_bt<1, 128, 4><<<6 * 64, 256, 0, stream>>>(
            big, w_pr + (size_t)l * 768 * 3072, pr_b + l * 768, h, nullptr, nullptr, nullptr,
            8192, 768, 3072);
    }
    ln_k<false><<<2048, 256, 0, stream>>>(h, lnfw, lnfb, outp);
}

// Round 9
// 1133.868 us; speedup vs baseline: 1.0618x; 1.0320x over previous
//
#include <hip/hip_runtime.h>
#include <hip/hip_bf16.h>

// ---------- types ----------
typedef __attribute__((ext_vector_type(8))) __bf16 bf16x8;
typedef __attribute__((ext_vector_type(4))) float f32x4;

typedef unsigned short u16;
typedef __attribute__((ext_vector_type(8))) u16 u16x8;

__device__ __forceinline__ u16 f2bf(float f) {
    unsigned int u = __float_as_uint(f);
    u += 0x7FFFu + ((u >> 16) & 1u);   // round-to-nearest-even
    return (u16)(u >> 16);
}

__device__ __forceinline__ float b2f(u16 u) {
    return __uint_as_float((unsigned int)u << 16);
}

__device__ __forceinline__ void g2l16(const void* g, void* l) {
    __builtin_amdgcn_global_load_lds(
        (const __attribute__((address_space(1))) void*)g,
        (__attribute__((address_space(3))) void*)l, 16, 0, 0);
}

// ---------- constants ----------
#define BB 8
#define SS 1024
#define EE 768
#define HH 12
#define HD 64
#define LL 4

// ---------- fp32 -> bf16 convert ----------
__global__ __launch_bounds__(256) void cvt_k(const float* __restrict__ in,
                                             u16* __restrict__ out, int n4) {
    for (int i = blockIdx.x * 256 + threadIdx.x; i < n4; i += gridDim.x * 256) {
        float4 v = ((const float4*)in)[i];
        ushort4 u;
        u.x = f2bf(v.x); u.y = f2bf(v.y); u.z = f2bf(v.z); u.w = f2bf(v.w);
        ((ushort4*)out)[i] = u;
    }
}

// ---------- embed: h = x + wpe[study_date] ----------
__global__ __launch_bounds__(256) void embed_k(const float* __restrict__ x,
                                               const int* __restrict__ sd,
                                               const float* __restrict__ wpe,
                                               float* __restrict__ h) {
    int idx = blockIdx.x * 256 + threadIdx.x;          // over 8192*192 float4s
    int e4 = idx % 192;
    int bs = idx / 192;
    int b = bs >> 10;
    int t = (bs >> 5) & 31;
    int date = sd[b * 32 + t];
    date = date < 0 ? 0 : (date > 49 ? 49 : date);
    float4 xv = ((const float4*)x)[idx];
    float4 pv = ((const float4*)wpe)[date * 192 + e4];
    float4 r; r.x = xv.x + pv.x; r.y = xv.y + pv.y; r.z = xv.z + pv.z; r.w = xv.w + pv.w;
    ((float4*)h)[idx] = r;
}

// ---------- layernorm: wave per token ----------
// R8: ADDP variant — h_token += p0_token + p1_token (bf16 split-K partials of
// the previous proj GEMM), write h back, then normalize. Folds the split-K
// reduction into the LN pass that already reads h.
template <bool BF16OUT, bool ADDP>
__global__ __launch_bounds__(256) void ln_k(const float* __restrict__ in,
                                            const float* __restrict__ w,
                                            const float* __restrict__ b,
                                            void* __restrict__ out,
                                            const u16* p0, const u16* p1,
                                            float* hback) {
    int tid = threadIdx.x, wv = tid >> 6, lane = tid & 63;
    int token = blockIdx.x * 4 + wv;
    const float4* ip = (const float4*)(in + (size_t)token * EE);
    float4 v[3];
#pragma unroll
    for (int p = 0; p < 3; p++) v[p] = ip[p * 64 + lane];
    if (ADDP) {
        const ushort4* q0 = (const ushort4*)(p0 + (size_t)token * EE);
        const ushort4* q1 = (const ushort4*)(p1 + (size_t)token * EE);
#pragma unroll
        for (int p = 0; p < 3; p++) {
            ushort4 a = q0[p * 64 + lane];
            ushort4 c = q1[p * 64 + lane];
            v[p].x += b2f(a.x) + b2f(c.x);
            v[p].y += b2f(a.y) + b2f(c.y);
            v[p].z += b2f(a.z) + b2f(c.z);
            v[p].w += b2f(a.w) + b2f(c.w);
        }
        if (hback) {
            float4* hp = (float4*)(hback + (size_t)token * EE);
#pragma unroll
            for (int p = 0; p < 3; p++) hp[p * 64 + lane] = v[p];
        }
    }
    float s = 0.f;
#pragma unroll
    for (int p = 0; p < 3; p++) s += v[p].x + v[p].y + v[p].z + v[p].w;
#pragma unroll
    for (int m = 1; m < 64; m <<= 1) s += __shfl_xor(s, m);
    float mean = s * (1.f / 768.f);
    float vs = 0.f;
#pragma unroll
    for (int p = 0; p < 3; p++) {
        float dx = v[p].x - mean, dy = v[p].y - mean, dz = v[p].z - mean, dw = v[p].w - mean;
        vs += dx * dx + dy * dy + dz * dz + dw * dw;
    }
#pragma unroll
    for (int m = 1; m < 64; m <<= 1) vs += __shfl_xor(vs, m);
    float rstd = rsqrtf(vs * (1.f / 768.f) + 1e-5f);
    const float4* wp = (const float4*)w;
    const float4* bp = (const float4*)b;
#pragma unroll
    for (int p = 0; p < 3; p++) {
        float4 wv4 = wp[p * 64 + lane], bv4 = bp[p * 64 + lane];
        float rx = (v[p].x - mean) * rstd * wv4.x + bv4.x;
        float ry = (v[p].y - mean) * rstd * wv4.y + bv4.y;
        float rz = (v[p].z - mean) * rstd * wv4.z + bv4.z;
        float rw = (v[p].w - mean) * rstd * wv4.w + bv4.w;
        if (BF16OUT) {
            ushort4 u; u.x = f2bf(rx); u.y = f2bf(ry); u.z = f2bf(rz); u.w = f2bf(rw);
            ((ushort4*)((u16*)out + (size_t)token * EE))[p * 64 + lane] = u;
        } else {
            float4 r; r.x = rx; r.y = ry; r.z = rz; r.w = rw;
            ((float4*)((float*)out + (size_t)token * EE))[p * 64 + lane] = r;
        }
    }
}

// ---------- GEMM: C[M,N] = A[M,K](bf16) * Bw[N,K]^T(bf16) + bias ----------
// 1-D grid, XCD-aware remap. vmcnt-gated pipeline (never vmcnt(0) in steady
// state). Per-shape config:
//   QKV/FC (BM=128): NST=3, PD=1, 48 KB -> 3 blocks/CU.
//   out    (BM=64):  NST=4, PD=2, 48 KB.
//   proj   (MODE 3): BM=128, NST=3, SPLITK=2 -> 768 blocks (3/CU, 48 iters);
//     halves write bf16 partials to separate buffers (NO atomics — R7 showed
//     f32 atomicAdd doubles WRITE and loses more than fill gains); reduction
//     h += p0 + p1 is fused into the next ln_k<_,true> (R8).
// R8 null result: proj NST=4 flat (70.1 vs 69.2) -> gate is NOT HBM-latency
// bound; model: per-CU LDS-port service x block-iters binds. Split-K cuts
// busy-CU block-iters 192 -> 144.
// R5: MODE-0 V-epilogue writes vT pi-permuted per 32-token tile (see attn_k).
// MODE 0: QKV epilogue  (q -> qT; k -> kT; v -> vT[B,H,HD,S] pi-permuted)
// MODE 1: residual      (hres[M,N] += C + bias)
// MODE 2: NewGELU       (outb[M,N] = bf16(gelu(C + bias)))
// MODE 3: split-K part  (part[M,N] = bf16(C + (ks==0 ? bias : 0)); part = ks ? vT : outb)
template <int MODE, int BM, int NST, int SPLITK>
__global__ __launch_bounds__(256) void gemm_bt(const u16* __restrict__ A,
                                               const u16* __restrict__ Bw,
                                               const float* __restrict__ bias,
                                               float* __restrict__ hres,
                                               u16* __restrict__ outb,
                                               u16* __restrict__ vT,
                                               u16* __restrict__ kT,
                                               int M, int N, int K) {
    constexpr int TM = BM / 32;              // acc m-tiles per wave (4 or 2)
    constexpr int PD = NST - 2;              // prefetch distance
    constexpr int ATILE = BM * 32;           // u16 per A stage
    constexpr int TILE = ATILE + 4096;       // u16 per stage (A+B)
    constexpr int SSTR = TILE * 2;           // stage stride bytes
    __shared__ u16 SM[NST * TILE];

    const int tid = threadIdx.x;
    const int lane = tid & 63, w = tid >> 6;
    const int quad = lane >> 4, l16 = lane & 15;

    // XCD-aware block remap (k-slice in the slowest bits)
    const int nx = N >> 7;
    const int ny = M / BM;
    int id = blockIdx.x;
    int ks = 0;
    if (SPLITK == 2) {
        const int half = ny * nx;
        ks = id >= half;
        id -= ks * half;
    }
    const int xcd = id & 7, s = id >> 3;
    const int yt = xcd * (ny >> 3) + s / nx;
    const int xt = s % nx;
    const int m0 = yt * BM, n0 = xt * 128;
    const int wm = (w >> 1) * (BM / 2), wn = (w & 1) * 64;
    const int kbase = ks * (K / SPLITK);

    f32x4 acc[TM][4];
#pragma unroll
    for (int i = 0; i < TM; i++)
#pragma unroll
        for (int j = 0; j < 4; j++) acc[i][j] = (f32x4){0.f, 0.f, 0.f, 0.f};

    const int swz = (quad ^ ((l16 >> 1) & 3)) * 8;
    const int nk = (K / SPLITK) >> 5;

    // staging: chunk c holds row (c>>2), k-chunk ((c&3)^((c>>3)&3))
    // B: 512 chunks, 2 per thread
    const int cB0 = w * 128 + lane, cB1 = cB0 + 64;
    const int rB0 = cB0 >> 2, gB0 = (((cB0 & 3) ^ ((cB0 >> 3) & 3)) * 8);
    const int rB1 = cB1 >> 2, gB1 = (((cB1 & 3) ^ ((cB1 >> 3) & 3)) * 8);
    const u16* Bp0 = Bw + (size_t)(n0 + rB0) * K + kbase + gB0;
    const u16* Bp1 = Bw + (size_t)(n0 + rB1) * K + kbase + gB1;
    char* lB0 = (char*)SM + ATILE * 2 + w * 2048;
    char* lB1 = lB0 + 1024;
    // A: BM*4 chunks (2 per thread at BM=128, 1 at BM=64)
    const int cA0 = (BM == 128) ? cB0 : tid;
    const int rA0 = cA0 >> 2, gA0 = (((cA0 & 3) ^ ((cA0 >> 3) & 3)) * 8);
    const u16* Ap0 = A + (size_t)(m0 + rA0) * K + kbase + gA0;
    char* lA0 = (char*)SM + ((BM == 128) ? w * 2048 : w * 1024);
    const int cA1 = cB1;
    const int rA1 = cA1 >> 2, gA1 = (((cA1 & 3) ^ ((cA1 >> 3) & 3)) * 8);
    const u16* Ap1 = A + (size_t)(m0 + rA1) * K + kbase + gA1;
    char* lA1 = (char*)SM + w * 2048 + 1024;

    // prologue: stage tiles 0..PD-1
#pragma unroll
    for (int p = 0; p < PD; p++) {
        g2l16(Ap0 + p * 32, lA0 + p * SSTR);
        if (BM == 128) g2l16(Ap1 + p * 32, lA1 + p * SSTR);
        g2l16(Bp0 + p * 32, lB0 + p * SSTR);
        g2l16(Bp1 + p * 32, lB1 + p * SSTR);
    }

    int rb = 0, wb = PD;
    for (int ki = 0; ki < nk; ki++) {
        if (ki + PD < nk) {
            const int kb = (ki + PD) << 5;
            const int bo = wb * SSTR;
            g2l16(Ap0 + kb, lA0 + bo);
            if (BM == 128) g2l16(Ap1 + kb, lA1 + bo);
            g2l16(Bp0 + kb, lB0 + bo);
            g2l16(Bp1 + kb, lB1 + bo);
        }
        // gate: tile ki landed when <= d tile-groups remain outstanding,
        // d = min(PD, nk-1-ki); loads/group = 4 (BM=128) or 3 (BM=64)
        {
            const int rem = nk - 1 - ki;
            const int d = rem < PD ? rem : PD;
            if (BM == 128) {
                if (PD == 2) {
                    if (d == 2)      __builtin_amdgcn_s_waitcnt(0x0F78);  // vmcnt(8)
                    else if (d == 1) __builtin_amdgcn_s_waitcnt(0x0F74);  // vmcnt(4)
                    else             __builtin_amdgcn_s_waitcnt(0x0F70);  // vmcnt(0)
                } else {
                    if (d == 1)      __builtin_amdgcn_s_waitcnt(0x0F74);  // vmcnt(4)
                    else             __builtin_amdgcn_s_waitcnt(0x0F70);  // vmcnt(0)
                }
            } else {
                if (d == 2)      __builtin_amdgcn_s_waitcnt(0x0F76);  // vmcnt(6)
                else if (d == 1) __builtin_amdgcn_s_waitcnt(0x0F73);  // vmcnt(3)
                else             __builtin_amdgcn_s_waitcnt(0x0F70);  // vmcnt(0)
            }
        }
        __builtin_amdgcn_s_barrier();

        const u16* Ab = (const u16*)SM + rb * TILE;
        const u16* Bb = Ab + ATILE;
        bf16x8 af[TM], bfr[4];
#pragma unroll
        for (int t = 0; t < TM; t++)
            af[t] = *(const bf16x8*)(Ab + (wm + t * 16 + l16) * 32 + swz);
#pragma unroll
        for (int t = 0; t < 4; t++)
            bfr[t] = *(const bf16x8*)(Bb + (wn + t * 16 + l16) * 32 + swz);
#pragma unroll
        for (int tm = 0; tm < TM; tm++)
#pragma unroll
            for (int tn = 0; tn < 4; tn++)
                acc[tm][tn] = __builtin_amdgcn_mfma_f32_16x16x32_bf16(
                    af[tm], bfr[tn], acc[tm][tn], 0, 0, 0);
        rb = (rb + 1 == NST) ? 0 : rb + 1;
        wb = (wb + 1 == NST) ? 0 : wb + 1;
    }

    // epilogue: C row = m0+wm+tm*16+quad*4+r ; col = n0+wn+tn*16+l16
#pragma unroll
    for (int tm = 0; tm < TM; tm++) {
        int rowm = m0 + wm + tm * 16 + quad * 4;
#pragma unroll
        for (int tn = 0; tn < 4; tn++) {
            int coln = n0 + wn + tn * 16 + l16;
            float bv = bias[coln];
            f32x4 v = acc[tm][tn];
            if (MODE == 0) {
                int b = rowm >> 10, s2 = rowm & 1023;
                if (coln < EE) {
                    int hh = coln >> 6, d = coln & 63;
                    u16* qp = outb + ((size_t)(b * HH + hh) * SS + s2) * HD + d;
#pragma unroll
                    for (int r = 0; r < 4; r++) qp[r * HD] = f2bf(v[r] + bv);
                } else if (coln < 2 * EE) {
                    int hh = (coln - EE) >> 6, d = (coln - EE) & 63;
                    u16* kp = kT + ((size_t)(b * HH + hh) * SS + s2) * HD + d;
#pragma unroll
                    for (int r = 0; r < 4; r++) kp[r * HD] = f2bf(v[r] + bv);
                } else {
                    int hh = (coln - 2 * EE) >> 6, d = (coln - 2 * EE) & 63;
                    // pi-permute within the 32-token tile (see attn_k PV layout)
                    int j0 = s2 & 31;
                    int k0 = (j0 < 16) ? ((j0 >> 2) * 8) : (((j0 - 16) >> 2) * 8 + 4);
                    int s2p = (s2 & ~31) | k0;
                    ushort4 pk;
                    pk.x = f2bf(v[0] + bv); pk.y = f2bf(v[1] + bv);
                    pk.z = f2bf(v[2] + bv); pk.w = f2bf(v[3] + bv);
                    *(ushort4*)(vT + (((size_t)((b * HH + hh) * HD + d)) << 10) + s2p) = pk;
                }
            } else if (MODE == 1) {
#pragma unroll
                for (int r = 0; r < 4; r++) {
                    size_t idx = (size_t)(rowm + r) * N + coln;
                    hres[idx] += v[r] + bv;
                }
            } else if (MODE == 2) {
#pragma unroll
                for (int r = 0; r < 4; r++) {
                    float x = v[r] + bv;
                    float t = x + 0.044715f * x * x * x;
                    float e = __expf(-1.5957691216057308f * t);  // exp(-2*sqrt(2/pi)*t)
                    float th = (1.f - e) / (1.f + e);
                    outb[(size_t)(rowm + r) * N + coln] = f2bf(0.5f * x * (1.f + th));
                }
            } else {
                // MODE 3: bf16 partial to outb (ks=0, +bias) or vT (ks=1)
                u16* pb = ks ? vT : outb;
                float badd = ks ? 0.f : bv;
#pragma unroll
                for (int r = 0; r < 4; r++)
                    pb[(size_t)(rowm + r) * N + coln] = f2bf(v[r] + badd);
            }
        }
    }
}

// ---------- flash attention (R5: swapped QK^T, lane-local softmax) ----------
// qT,kT: [B,H,S,HD] bf16   vT: [B,H,HD,S] bf16 (pi-permuted per 32-tok tile)
// o: [B*S, 768] bf16
// block = 4 waves = one (b, head, 64 q-rows); K/V staged in LDS.
// Swapped QK: mfma(K,Q) -> S[key][q], col=l16=q. Each lane's 8 scores all
// belong to q=l16 (keys quad*4+r and 16+quad*4+r) -> softmax is 7 local ops +
// 2 shfl_xor (x16,x32) per reduction instead of 16 shuffles; P never touches
// LDS (the lane's exp'd values ARE its PV A-fragment, in pi key order).
// Defer-max (THR=8): skip of-rescale when tile max grows <= 8 (P <= e^8,
// fine in bf16; checked wave-uniformly via __all each tile).
__global__ __launch_bounds__(256) void attn_k(const u16* __restrict__ qT,
                                              const u16* __restrict__ kT,
                                              const u16* __restrict__ vT,
                                              u16* __restrict__ o) {
    __shared__ u16 Ks[2048];        // 32 tokens x 64 d, 16B chunks swizzled
    __shared__ u16 Vs[2048];        // 64 d x 32 pi-slots, 16B chunks swizzled
    int tid = threadIdx.x, w = tid >> 6, lane = tid & 63;
    int quad = lane >> 4, l16 = lane & 15;
    int blk = blockIdx.x;
    int qg = 15 - (blk / 96);       // largest q-groups dispatch first (load balance)
    int bh = blk % 96;              // b*12 + h
    int b = bh / HH, hh = bh % HH;
    int q0 = qg * 64;
    int kend_blk = q0 + 64;
    int kend_w = q0 + ((w >> 1) ? 64 : 32);

    const u16* qbase = qT + ((size_t)bh * SS + q0 + w * 16 + l16) * HD + quad * 8;
    bf16x8 qf0 = *(const bf16x8*)(qbase);
    bf16x8 qf1 = *(const bf16x8*)(qbase + 32);

    f32x4 of[4];
#pragma unroll
    for (int i = 0; i < 4; i++) of[i] = (f32x4){0.f, 0.f, 0.f, 0.f};
    float mrun = -__builtin_inff(), lrun = 0.f;

    // staging addresses: slot s (=tid) of Ks holds K[token=s>>3][dchunk=(s&7)^(token&7)]
    int tK = tid >> 3, dcK = ((tid & 7) ^ (tK & 7));
    const u16* kg = kT + ((size_t)bh * SS + tK) * HD + dcK * 8;
    char* kl = (char*)Ks + w * 1024;
    // slot s of Vs holds V[d=s>>2][pi-tokchunk=(s&3)^((d>>1)&3)]
    int dV = tid >> 2, tcV = ((tid & 3) ^ ((dV >> 1) & 3));
    const u16* vg = vT + ((size_t)bh * HD + dV) * SS + tcV * 8;
    char* vl = (char*)Vs + w * 1024;

    for (int kb = 0; kb < kend_blk; kb += 32) {
        g2l16(kg + (size_t)kb * HD, kl);
        g2l16(vg + kb, vl);
        __syncthreads();
        if (kb < kend_w) {
            int t0 = l16, t1 = 16 + l16;
            bf16x8 k00 = *(const bf16x8*)(Ks + (t0 * 8 + (quad ^ (l16 & 7))) * 8);
            bf16x8 k01 = *(const bf16x8*)(Ks + (t0 * 8 + ((4 + quad) ^ (l16 & 7))) * 8);
            bf16x8 k10 = *(const bf16x8*)(Ks + (t1 * 8 + (quad ^ (l16 & 7))) * 8);
            bf16x8 k11 = *(const bf16x8*)(Ks + (t1 * 8 + ((4 + quad) ^ (l16 & 7))) * 8);
            // swapped: D[key][q]  (sT0 keys quad*4+r, sT1 keys 16+quad*4+r; col=l16=q)
            f32x4 sT0 = (f32x4){0.f, 0.f, 0.f, 0.f};
            f32x4 sT1 = (f32x4){0.f, 0.f, 0.f, 0.f};
            sT0 = __builtin_amdgcn_mfma_f32_16x16x32_bf16(k00, qf0, sT0, 0, 0, 0);
            sT0 = __builtin_amdgcn_mfma_f32_16x16x32_bf16(k01, qf1, sT0, 0, 0, 0);
            sT1 = __builtin_amdgcn_mfma_f32_16x16x32_bf16(k10, qf0, sT1, 0, 0, 0);
            sT1 = __builtin_amdgcn_mfma_f32_16x16x32_bf16(k11, qf1, sT1, 0, 0, 0);

            float a0[4], a1[4];
#pragma unroll
            for (int r = 0; r < 4; r++) { a0[r] = sT0[r] * 0.125f; a1[r] = sT1[r] * 0.125f; }
            // tile max for q=l16: 7 local + 2 cross-quad shuffles
            float mx = fmaxf(fmaxf(fmaxf(a0[0], a0[1]), fmaxf(a0[2], a0[3])),
                             fmaxf(fmaxf(a1[0], a1[1]), fmaxf(a1[2], a1[3])));
            mx = fmaxf(mx, __shfl_xor(mx, 16));
            mx = fmaxf(mx, __shfl_xor(mx, 32));
            // defer-max: only rescale when max grew by > 8
            if (!__all(mx - mrun <= 8.0f)) {
                float mnew = fmaxf(mrun, mx);
                float alpha = __expf(mrun - mnew);
                mrun = mnew;
                lrun *= alpha;
                float al[4];
#pragma unroll
                for (int r = 0; r < 4; r++) al[r] = __shfl(alpha, quad * 4 + r);
#pragma unroll
                for (int n4 = 0; n4 < 4; n4++) {
                    of[n4][0] *= al[0]; of[n4][1] *= al[1];
                    of[n4][2] *= al[2]; of[n4][3] *= al[3];
                }
            }
            float p0[4], p1[4];
#pragma unroll
            for (int r = 0; r < 4; r++) {
                p0[r] = __expf(a0[r] - mrun);
                p1[r] = __expf(a1[r] - mrun);
            }
            float ps = ((p0[0] + p0[1]) + (p0[2] + p0[3])) +
                       ((p1[0] + p1[1]) + (p1[2] + p1[3]));
            ps += __shfl_xor(ps, 16);
            ps += __shfl_xor(ps, 32);
            lrun += ps;
            // PV A-frag: lane-local (pi key order: e<4 -> key quad*4+e, else 16+quad*4+e-4)
            union { u16x8 u; bf16x8 v; } pa;
            pa.u[0] = f2bf(p0[0]); pa.u[1] = f2bf(p0[1]);
            pa.u[2] = f2bf(p0[2]); pa.u[3] = f2bf(p0[3]);
            pa.u[4] = f2bf(p1[0]); pa.u[5] = f2bf(p1[1]);
            pa.u[6] = f2bf(p1[2]); pa.u[7] = f2bf(p1[3]);
#pragma unroll
            for (int n4 = 0; n4 < 4; n4++) {
                int d = n4 * 16 + l16;
                bf16x8 vf = *(const bf16x8*)(Vs + (d * 4 + (quad ^ ((d >> 1) & 3))) * 8);
                of[n4] = __builtin_amdgcn_mfma_f32_16x16x32_bf16(pa.v, vf, of[n4], 0, 0, 0);
            }
        }
        __syncthreads();
    }

    float linv[4];
#pragma unroll
    for (int r = 0; r < 4; r++) linv[r] = 1.f / __shfl(lrun, quad * 4 + r);
#pragma unroll
    for (int n4 = 0; n4 < 4; n4++)
#pragma unroll
        for (int r = 0; r < 4; r++)
            o[(size_t)(b * SS + q0 + w * 16 + quad * 4 + r) * EE + hh * HD + n4 * 16 + l16] =
                f2bf(of[n4][r] * linv[r]);
}

// ---------- launcher ----------
extern "C" void kernel_launch(void* const* d_in, const int* in_sizes, int n_in,
                              void* d_out, int out_size, void* d_ws, size_t ws_size,
                              hipStream_t stream) {
    const float* x     = (const float*)d_in[0];
    const int*   sd    = (const int*)d_in[1];
    const float* wpe   = (const float*)d_in[2];
    const float* ln1w  = (const float*)d_in[3];
    const float* ln1b  = (const float*)d_in[4];
    const float* in_w  = (const float*)d_in[5];
    const float* in_b  = (const float*)d_in[6];
    const float* out_w = (const float*)d_in[7];
    const float* out_b = (const float*)d_in[8];
    const float* ln2w  = (const float*)d_in[9];
    const float* ln2b  = (const float*)d_in[10];
    const float* fc_w  = (const float*)d_in[11];
    const float* fc_b  = (const float*)d_in[12];
    const float* pr_w  = (const float*)d_in[13];
    const float* pr_b  = (const float*)d_in[14];
    const float* lnfw  = (const float*)d_in[15];
    const float* lnfb  = (const float*)d_in[16];
    float* outp = (float*)d_out;

    char* ws = (char*)d_ws;
    float* h   = (float*)ws;                        // 25,165,824 B
    u16* ybuf  = (u16*)(ws + 25165824);             // 12,582,912 B
    u16* big   = (u16*)(ws + 37748736);             // 50,331,648 B (qT+kT / fc act)
    u16* qT    = big;                               // 6,291,456 elems
    u16* kT    = big + 6291456;                     // 6,291,456 elems
    u16* vT    = (u16*)(ws + 88080384);             // 12,582,912 B
    u16* wb    = (u16*)(ws + 100663296);            // 56,623,104 B
    u16* w_in  = wb;                                // 4*2304*768
    u16* w_out = w_in + 7077888;                    // 4*768*768
    u16* w_fc  = w_out + 2359296;                   // 4*3072*768
    u16* w_pr  = w_fc + 9437184;                    // 4*768*3072

    cvt_k<<<1024, 256, 0, stream>>>(in_w,  w_in,  7077888 / 4);
    cvt_k<<<1024, 256, 0, stream>>>(out_w, w_out, 2359296 / 4);
    cvt_k<<<1024, 256, 0, stream>>>(fc_w,  w_fc,  9437184 / 4);
    cvt_k<<<1024, 256, 0, stream>>>(pr_w,  w_pr,  9437184 / 4);
    embed_k<<<6144, 256, 0, stream>>>(x, sd, wpe, h);

    for (int l = 0; l < LL; l++) {
        // ln1: layer 0 plain; layers 1..3 fuse the previous proj's split-K
        // reduction (h += p0(ybuf) + p1(vT)) with h writeback.
        if (l == 0)
            ln_k<true, false><<<2048, 256, 0, stream>>>(
                h, ln1w + l * EE, ln1b + l * EE, ybuf, nullptr, nullptr, nullptr);
        else
            ln_k<true, true><<<2048, 256, 0, stream>>>(
                h, ln1w + l * EE, ln1b + l * EE, ybuf, ybuf, vT, h);
        gemm_bt<0, 128, 3, 1><<<18 * 64, 256, 0, stream>>>(
            ybuf, w_in + (size_t)l * 2304 * 768, in_b + l * 2304, nullptr, qT, vT, kT,
            8192, 2304, 768);
        attn_k<<<1536, 256, 0, stream>>>(qT, kT, vT, ybuf);
        gemm_bt<1, 64, 4, 1><<<6 * 128, 256, 0, stream>>>(
            ybuf, w_out + (size_t)l * 768 * 768, out_b + l * 768, h, nullptr, nullptr, nullptr,
            8192, 768, 768);
        ln_k<true, false><<<2048, 256, 0, stream>>>(
            h, ln2w + l * EE, ln2b + l * EE, ybuf, nullptr, nullptr, nullptr);
        gemm_bt<2, 128, 3, 1><<<24 * 64, 256, 0, stream>>>(
            ybuf, w_fc + (size_t)l * 3072 * 768, fc_b + l * 3072, nullptr, big, nullptr, nullptr,
            8192, 3072, 768);
        // proj split-K=2: part0 -> ybuf (+bias), part1 -> vT; reduced by next ln1 / lnf
        gemm_bt<3, 128, 3, 2><<<2 * 6 * 64, 256, 0, stream>>>(
            big, w_pr + (size_t)l * 768 * 3072, pr_b + l * 768, nullptr, ybuf, vT, nullptr,
            8192, 768, 3072);
    }
    // final LN fuses the last proj reduction (no h writeback needed)
    ln_k<false, true><<<2048, 256, 0, stream>>>(
        h, lnfw, lnfb, outp, ybuf, vT, nullptr);
}